// Round 1
// 73.598 us; speedup vs baseline: 1.0162x; 1.0162x over previous
//
#include <hip/hip_runtime.h>
#include <math.h>

// Quantum circuit collapses to z_q[b] = r(b)^T A_q r(b) with
//   r = kron([c0,s0],[c1,s1]), c_i = cos(noise_i*pi/2), s_i = sin(noise_i*pi/2).
// Since A_q is symmetric and r is a Kronecker product, z_q is bilinear in the
// moment vectors  u = [c0^2, c0*s0, s0^2],  v = [c1^2, c1*s1, s1^2].
// Double-angle:  c^2 = (1+C)/2, s^2 = (1-C)/2, c*s = S/2  with C = cos(pi*n),
// S = sin(pi*n)  =>  z_q = x^T K_q y,  x = [1, C0, S0], y = [1, C1, S1].
// K_q (9 floats per wire) depends only on q_weights -> computed once by a
// 1-thread prep kernel into d_ws; the streaming kernel is 2 sincos + 16 FMA
// per sample, no LDS, no barrier.

struct Cx { float re, im; };
__device__ inline Cx cmul(Cx a, Cx b){ return {a.re*b.re - a.im*b.im, a.re*b.im + a.im*b.re}; }
__device__ inline Cx cmadd2(Cx a, Cx x, Cx b, Cx y){
  Cx p = cmul(a,x), q = cmul(b,y);
  return { p.re + q.re, p.im + q.im };
}

__global__ void qc_prep(const float* __restrict__ w, float* __restrict__ K) {
  if (threadIdx.x != 0) return;

  Cx U[4][4];
  for (int r = 0; r < 4; ++r)
    for (int c = 0; c < 4; ++c)
      U[r][c] = { (r == c) ? 1.f : 0.f, 0.f };

  for (int l = 0; l < 2; ++l) {
    Cx g[2][2][2];  // [wire][i][j]
    for (int q = 0; q < 2; ++q) {
      float phi = w[l*6 + q*3 + 0];
      float th  = w[l*6 + q*3 + 1];
      float om  = w[l*6 + q*3 + 2];
      float st, ct; sincosf(0.5f*th, &st, &ct);
      float sp, cp; sincosf(0.5f*(phi+om), &sp, &cp);
      float sm, cm; sincosf(0.5f*(phi-om), &sm, &cm);
      g[q][0][0] = {  cp*ct, -sp*ct };
      g[q][0][1] = { -cm*st, -sm*st };
      g[q][1][0] = {  cm*st, -sm*st };
      g[q][1][1] = {  cp*ct,  sp*ct };
    }
    // U <- (g0 (x) I) * U
    for (int c = 0; c < 4; ++c)
      for (int k = 0; k < 2; ++k) {
        Cx x0 = U[k][c], x1 = U[2+k][c];
        U[k][c]   = cmadd2(g[0][0][0], x0, g[0][0][1], x1);
        U[2+k][c] = cmadd2(g[0][1][0], x0, g[0][1][1], x1);
      }
    // U <- (I (x) g1) * U
    for (int c = 0; c < 4; ++c)
      for (int j = 0; j < 2; ++j) {
        Cx x0 = U[2*j][c], x1 = U[2*j+1][c];
        U[2*j][c]   = cmadd2(g[1][0][0], x0, g[1][0][1], x1);
        U[2*j+1][c] = cmadd2(g[1][1][0], x0, g[1][1][1], x1);
      }
    // CNOT(q0->q1): swap rows 2,3 ; CNOT(q1->q0): swap rows 1,3
    for (int c = 0; c < 4; ++c) { Cx t = U[2][c]; U[2][c] = U[3][c]; U[3][c] = t; }
    for (int c = 0; c < 4; ++c) { Cx t = U[1][c]; U[1][c] = U[3][c]; U[3][c] = t; }
  }

  // V = U * D, D = diag(1, -i, -i, -1)
  for (int r = 0; r < 4; ++r) {
    Cx t;
    t = U[r][1]; U[r][1] = {  t.im, -t.re };
    t = U[r][2]; U[r][2] = {  t.im, -t.re };
    t = U[r][3]; U[r][3] = { -t.re, -t.im };
  }

  // A_q[a][b] = sum_r zq[r] * Re( conj(V[r][a]) V[r][b] )   (symmetric)
  const float z0s[4] = { 1.f,  1.f, -1.f, -1.f };
  const float z1s[4] = { 1.f, -1.f,  1.f, -1.f };
  float A[2][16];
  for (int a = 0; a < 4; ++a)
    for (int b = 0; b < 4; ++b) {
      float a0 = 0.f, a1 = 0.f;
      for (int r = 0; r < 4; ++r) {
        float d = U[r][a].re*U[r][b].re + U[r][a].im*U[r][b].im;
        a0 += z0s[r]*d;
        a1 += z1s[r]*d;
      }
      A[0][a*4 + b] = a0;
      A[1][a*4 + b] = a1;
    }

  // Fold Kronecker structure:  z = sum_{a,b in 0..2} M[a][b] u_a v_b
  //   u = [c0^2, c0 s0, s0^2], v likewise. (off-diagonals of A appear twice)
  float M[2][9];
  for (int q = 0; q < 2; ++q) {
    const float* a = A[q];
    M[q][0] = a[0];            // (00,00)
    M[q][1] = 2.f*a[1];        // (00,01)+(01,00)
    M[q][2] = a[5];            // (01,01)
    M[q][3] = 2.f*a[2];        // (00,10)+(10,00)
    M[q][4] = 2.f*(a[3]+a[6]); // (00,11)+(11,00)+(01,10)+(10,01)
    M[q][5] = 2.f*a[7];        // (01,11)+(11,01)
    M[q][6] = a[10];           // (10,10)
    M[q][7] = 2.f*a[11];       // (10,11)+(11,10)
    M[q][8] = a[15];           // (11,11)
  }

  // Double-angle basis change: [c^2, c s, s^2] = T [1, C, S]^T
  const float T[3][3] = { {0.5f, 0.5f, 0.f},
                          {0.f,  0.f,  0.5f},
                          {0.5f, -0.5f, 0.f} };
  for (int q = 0; q < 2; ++q)
    for (int c = 0; c < 3; ++c)
      for (int d = 0; d < 3; ++d) {
        float acc = 0.f;
        for (int a = 0; a < 3; ++a)
          for (int b = 0; b < 3; ++b)
            acc += T[a][c] * M[q][a*3+b] * T[b][d];
        K[q*9 + c*3 + d] = acc;
      }
}

__device__ inline float evalK(const float* __restrict__ k,
                              float C0, float S0, float C1, float S1) {
  float t0 = fmaf(k[2], S1, fmaf(k[1], C1, k[0]));
  float t1 = fmaf(k[5], S1, fmaf(k[4], C1, k[3]));
  float t2 = fmaf(k[8], S1, fmaf(k[7], C1, k[6]));
  return fmaf(S0, t2, fmaf(C0, t1, t0));
}

__global__ __launch_bounds__(256) void qc_main(const float* __restrict__ noise,
                                               const float* __restrict__ Kg,
                                               float* __restrict__ out,
                                               int nQuads) {
  // 18 uniform coefficients -> registers (uniform address, scalar-load friendly)
  float k0[9], k1[9];
  #pragma unroll
  for (int i = 0; i < 9; ++i) { k0[i] = Kg[i]; k1[i] = Kg[9 + i]; }

  const float PI = 3.14159265358979323846f;
  const float4* __restrict__ in4  = (const float4*)noise;
  float4* __restrict__ out4 = (float4*)out;

  int i = blockIdx.x * blockDim.x + threadIdx.x;
  if (i >= nQuads) return;

  float4 v = in4[i];   // two samples: (v.x,v.y), (v.z,v.w)
  float4 o;
  {
    float S0, C0, S1, C1;
    __sincosf(v.x * PI, &S0, &C0);
    __sincosf(v.y * PI, &S1, &C1);
    o.x = evalK(k0, C0, S0, C1, S1);
    o.y = evalK(k1, C0, S0, C1, S1);
  }
  {
    float S0, C0, S1, C1;
    __sincosf(v.z * PI, &S0, &C0);
    __sincosf(v.w * PI, &S1, &C1);
    o.z = evalK(k0, C0, S0, C1, S1);
    o.w = evalK(k1, C0, S0, C1, S1);
  }
  out4[i] = o;
}

extern "C" void kernel_launch(void* const* d_in, const int* in_sizes, int n_in,
                              void* d_out, int out_size, void* d_ws, size_t ws_size,
                              hipStream_t stream) {
  const float* noise = (const float*)d_in[0];   // [B,2] float32
  const float* w     = (const float*)d_in[1];   // [2,2,3] float32
  float* out         = (float*)d_out;           // [B,2] float32
  float* K           = (float*)d_ws;            // 18 floats

  qc_prep<<<1, 64, 0, stream>>>(w, K);

  int nQuads  = in_sizes[0] / 4;                // (B*2 floats) / 4 -> float4 count
  int threads = 256;
  int blocks  = (nQuads + threads - 1) / threads;  // exact grid, 1 float4/thread
  qc_main<<<blocks, threads, 0, stream>>>(noise, K, out, nQuads);
}